// Round 8
// baseline (273.376 us; speedup 1.0000x reference)
//
#include <hip/hip_runtime.h>
#include <math.h>

#define D_MODEL 2048
#define NUM_HEADS 16
#define HEAD_DIM 128
#define BB 2
#define TT 2048
#define QKV_N 2304
#define KOFF 2048
#define VOFF 2176

typedef __attribute__((ext_vector_type(8))) short short8;
typedef __attribute__((ext_vector_type(4))) float f32x4;

static __device__ __forceinline__ short f2bf(float f) {
  union { float f; unsigned u; } x; x.f = f;
  unsigned r = (x.u + 0x7FFFu + ((x.u >> 16) & 1u)) >> 16;
  return (short)r;
}

#define GLD16(gp, lp)                                              \
  __builtin_amdgcn_global_load_lds(                                \
      (const __attribute__((address_space(1))) void*)(gp),         \
      (__attribute__((address_space(3))) void*)(lp), 16, 0, 0)

// 8-row-band column-major block swizzle: temporally adjacent blocks share an
// A band -> L2 locality (round 7: FETCH 89->46 MB).
static __device__ __forceinline__ void swizzle_xy(int& bx, int& by) {
  const int gx = gridDim.x;
  const int lin = blockIdx.y * gx + blockIdx.x;
  const int band = lin / (gx * 8);
  const int rem = lin - band * gx * 8;
  by = band * 8 + (rem & 7);
  bx = rem >> 3;
}

// ---------------------------------------------------------------------------
// GEMM1 fused: qkv = x @ W_qkv, RoPE in-epilogue, V written transposed.
// Round-0's 2-barrier BK=64 structure (68.5 us measured round 7, best of 4
// variants). Bank-conflict XOR swizzle kept (4.7M conflict cyc -> 0).
// ---------------------------------------------------------------------------
__global__ __launch_bounds__(256) void gemm_qkv_rope(
    const short* __restrict__ A, const short* __restrict__ Bt,
    short* __restrict__ qkv, short* __restrict__ Vtb,
    const float* __restrict__ sin_t, const float* __restrict__ cos_t)
{
  __shared__ short As[2 * 128 * 32];  // [kc][m][32], 16 KB
  __shared__ short Bs[2 * 128 * 32];  // [kc][n][32], 16 KB
  const int K = D_MODEL;

  int bx, by;
  swizzle_xy(bx, by);

  const int tid = threadIdx.x;
  const int w = tid >> 6, l = tid & 63;
  const int quad = l >> 4, l16 = l & 15;
  const int wm = w >> 1, wn = w & 1;
  const int m0 = by * 128, n0 = bx * 128;

  f32x4 acc[4][4];
#pragma unroll
  for (int i = 0; i < 4; i++)
#pragma unroll
    for (int j = 0; j < 4; j++) acc[i][j] = (f32x4){0.f, 0.f, 0.f, 0.f};

  const int cswz = ((l & 3) ^ ((l >> 3) & 3)) * 8;
  const short* aA = A + (size_t)(m0 + w * 32 + (l >> 2)) * K + cswz;
  const short* aB = Bt + (size_t)(n0 + w * 32 + (l >> 2)) * K + cswz;
  short* lA = As + w * 1024;  // wave-uniform LDS bases
  short* lB = Bs + w * 1024;

  const int aswz = (quad ^ ((l16 >> 1) & 3)) * 8;
  const short* Ard = As + (size_t)(wm * 64 + l16) * 32 + aswz;
  const short* Brd = Bs + (size_t)(wn * 16 + l16) * 32 + aswz;

  for (int k0 = 0; k0 < K; k0 += 64) {
    __syncthreads();
#pragma unroll
    for (int h = 0; h < 2; h++) {  // two 32-k panels
      const int go = k0 + h * 32;
      const int lo = h * 4096;
      GLD16(aA + go, lA + lo);
      GLD16(aA + go + (size_t)16 * K, lA + lo + 512);
      GLD16(aB + go, lB + lo);
      GLD16(aB + go + (size_t)16 * K, lB + lo + 512);
    }
    __syncthreads();

#pragma unroll
    for (int kc = 0; kc < 2; kc++) {
      short8 af[4], bf[4];
#pragma unroll
      for (int mi = 0; mi < 4; mi++)
        af[mi] = *(const short8*)(Ard + kc * 4096 + mi * 512);
#pragma unroll
      for (int ni = 0; ni < 4; ni++)
        bf[ni] = *(const short8*)(Brd + kc * 4096 + ni * 1024);
#pragma unroll
      for (int mi = 0; mi < 4; mi++)
#pragma unroll
        for (int ni = 0; ni < 4; ni++)
          acc[mi][ni] =
              __builtin_amdgcn_mfma_f32_16x16x32_bf16(af[mi], bf[ni], acc[mi][ni], 0, 0, 0);
    }
  }

  const int colbase = wn * 16 + l16;      // in [0,32)
  const bool is_v = (n0 == VOFF);         // V head: no rope, transposed out

#pragma unroll
  for (int mi = 0; mi < 4; mi++) {
#pragma unroll
    for (int r = 0; r < 4; r++) {
      const int row = m0 + wm * 64 + mi * 16 + quad * 4 + r;
      const int b = row >> 11, t = row & (TT - 1);
#pragma unroll
      for (int ni = 0; ni < 2; ni++) {
        const int cloc = ni * 32 + colbase;   // in [0,64)
        const float c1 = acc[mi][ni][r];
        const float c2 = acc[mi][ni + 2][r];
        if (!is_v) {
          const float sn = sin_t[t * 64 + cloc];
          const float cs = cos_t[t * 64 + cloc];
          short* op = qkv + (size_t)row * QKV_N + n0 + cloc;
          op[0]  = f2bf(c1 * cs - c2 * sn);
          op[64] = f2bf(c2 * cs + c1 * sn);
        } else {
          Vtb[((size_t)(b * 128 + cloc) << 11) + t]      = f2bf(c1);
          Vtb[((size_t)(b * 128 + cloc + 64) << 11) + t] = f2bf(c2);
        }
      }
    }
  }
}

// ---------------------------------------------------------------------------
// GEMM2: out = attn_bf @ Wout_t^T, fp32 out. Round-0 BK=64 2-barrier + swizzle.
// ---------------------------------------------------------------------------
__global__ __launch_bounds__(256) void gemm_mfma_bt(
    const short* __restrict__ A, const short* __restrict__ Bt,
    float* __restrict__ C, int M, int N, int K)
{
  __shared__ short As[2 * 128 * 32];
  __shared__ short Bs[2 * 128 * 32];

  int bx, by;
  swizzle_xy(bx, by);

  const int tid = threadIdx.x;
  const int w = tid >> 6, l = tid & 63;
  const int quad = l >> 4, l16 = l & 15;
  const int wm = w >> 1, wn = w & 1;
  const int m0 = by * 128, n0 = bx * 128;

  f32x4 acc[4][4];
#pragma unroll
  for (int i = 0; i < 4; i++)
#pragma unroll
    for (int j = 0; j < 4; j++) acc[i][j] = (f32x4){0.f, 0.f, 0.f, 0.f};

  const int cswz = ((l & 3) ^ ((l >> 3) & 3)) * 8;
  const short* aA = A + (size_t)(m0 + w * 32 + (l >> 2)) * K + cswz;
  const short* aB = Bt + (size_t)(n0 + w * 32 + (l >> 2)) * K + cswz;
  short* lA = As + w * 1024;
  short* lB = Bs + w * 1024;

  const int aswz = (quad ^ ((l16 >> 1) & 3)) * 8;
  const short* Ard = As + (size_t)(wm * 64 + l16) * 32 + aswz;
  const short* Brd = Bs + (size_t)(wn * 64 + l16) * 32 + aswz;

  for (int k0 = 0; k0 < K; k0 += 64) {
    __syncthreads();
#pragma unroll
    for (int h = 0; h < 2; h++) {
      const int go = k0 + h * 32;
      const int lo = h * 4096;
      GLD16(aA + go, lA + lo);
      GLD16(aA + go + (size_t)16 * K, lA + lo + 512);
      GLD16(aB + go, lB + lo);
      GLD16(aB + go + (size_t)16 * K, lB + lo + 512);
    }
    __syncthreads();

#pragma unroll
    for (int kc = 0; kc < 2; kc++) {
      short8 af[4], bf[4];
#pragma unroll
      for (int mi = 0; mi < 4; mi++)
        af[mi] = *(const short8*)(Ard + kc * 4096 + mi * 512);
#pragma unroll
      for (int ni = 0; ni < 4; ni++)
        bf[ni] = *(const short8*)(Brd + kc * 4096 + ni * 512);
#pragma unroll
      for (int mi = 0; mi < 4; mi++)
#pragma unroll
        for (int ni = 0; ni < 4; ni++)
          acc[mi][ni] =
              __builtin_amdgcn_mfma_f32_16x16x32_bf16(af[mi], bf[ni], acc[mi][ni], 0, 0, 0);
    }
  }

#pragma unroll
  for (int mi = 0; mi < 4; mi++) {
#pragma unroll
    for (int ni = 0; ni < 4; ni++) {
#pragma unroll
      for (int r = 0; r < 4; r++) {
        const int row = m0 + wm * 64 + mi * 16 + quad * 4 + r;
        const int col = n0 + wn * 64 + ni * 16 + l16;
        C[(size_t)row * N + col] = acc[mi][ni][r];
      }
    }
  }
}

// ---------------------------------------------------------------------------
// Fused prep: convert x -> bf16, transpose+convert W_qkv and W_out.
// ---------------------------------------------------------------------------
#define XB_BLOCKS 8192                 // 4096*2048/4/256
#define WQ_BLOCKS (72 * 64)            // (2304/32)*(2048/32)
#define WO_BLOCKS (64 * 64)

__global__ __launch_bounds__(256) void prep_all(
    const float* __restrict__ x, short* __restrict__ xb,
    const float* __restrict__ Wq, short* __restrict__ Wqt,
    const float* __restrict__ Wo, short* __restrict__ Wot)
{
  const int bid = blockIdx.x;
  const int tid = threadIdx.x;

  if (bid < XB_BLOCKS) {
    const size_t i4 = (size_t)bid * 256 + tid;
    float4 v = *(const float4*)(x + i4 * 4);
    short4 o;
    o.x = f2bf(v.x); o.y = f2bf(v.y); o.z = f2bf(v.z); o.w = f2bf(v.w);
    *(short4*)(xb + i4 * 4) = o;
    return;
  }

  __shared__ float t[32][33];
  const float* W;
  short* Wt;
  int N, tile, ntx;
  if (bid < XB_BLOCKS + WQ_BLOCKS) {
    tile = bid - XB_BLOCKS; W = Wq; Wt = Wqt; N = QKV_N; ntx = 72;
  } else {
    tile = bid - XB_BLOCKS - WQ_BLOCKS; W = Wo; Wt = Wot; N = D_MODEL; ntx = 64;
  }
  const int K = D_MODEL;
  const int bx = tile % ntx, byy = tile / ntx;
  const int tx = tid & 31, ty = tid >> 5;
  const int n0 = bx * 32, k0 = byy * 32;
#pragma unroll
  for (int j = 0; j < 4; j++)
    t[ty + j * 8][tx] = W[(size_t)(k0 + ty + j * 8) * N + n0 + tx];
  __syncthreads();
#pragma unroll
  for (int j = 0; j < 4; j++)
    Wt[(size_t)(n0 + ty + j * 8) * K + k0 + tx] = f2bf(t[tx][ty + j * 8]);
}

// ---------------------------------------------------------------------------
// Flash MQA attention, round-7 GLD16 structure + 2 HEADS PER BLOCK (round 8).
// MQA: all heads share K/V, so one staged K/V tile now serves two heads'
// QK->softmax->PV (mask/doc logic is head-independent; Pbuf is wave-private
// so the per-head sequence needs no extra barriers). Staging cost per unit
// compute halves; per-tile MFMA cluster doubles (24->48). Grid (32,8,2) =
// 512 blocks = exactly 2.0/CU, no tail. __launch_bounds__(256,2): budget
// 256 VGPR/wave (live set ~150; round-5 lesson: guard allocator explicitly).
// ---------------------------------------------------------------------------
#define PSTR 72

__global__ __launch_bounds__(256, 2) void attn_mfma(
    const short* __restrict__ qkv, const short* __restrict__ Vtb,
    const int* __restrict__ doc_ids, short* __restrict__ attn_out)
{
  __shared__ short Ks[64 * 128];     // 16 KB, linear + chunk-XOR
  __shared__ short Vt[128 * 64];     // 16 KB, linear + chunk-XOR
  __shared__ short Pbuf[4 * 16 * PSTR];
  __shared__ int doc_s[64];

  const int qt = blockIdx.x, h0 = blockIdx.y * 2, b = blockIdx.z;
  const int q0 = qt * 64;
  const int tid = threadIdx.x;
  const int w = tid >> 6;
  const int lane = tid & 63;
  const int quad = lane >> 4, l16 = lane & 15;

  // Q fragments for both heads
  short8 Qf[2][4];
#pragma unroll
  for (int hh = 0; hh < 2; hh++) {
    const short* qp = qkv + (size_t)(b * TT + q0 + w * 16 + l16) * QKV_N
                      + (h0 + hh) * HEAD_DIM + quad * 8;
#pragma unroll
    for (int kc = 0; kc < 4; kc++) Qf[hh][kc] = *(const short8*)(qp + kc * 32);
  }

  const int docmin_q = doc_ids[b * TT + q0];
  const int docmax_q = doc_ids[b * TT + q0 + 63];

  int qg[4], mydoc[4];
#pragma unroll
  for (int r = 0; r < 4; r++) {
    qg[r] = q0 + w * 16 + quad * 4 + r;
    mydoc[r] = doc_ids[b * TT + qg[r]];
  }
  float l_i[2][4];
  f32x4 O[2][8];
#pragma unroll
  for (int hh = 0; hh < 2; hh++) {
#pragma unroll
    for (int r = 0; r < 4; r++) l_i[hh][r] = 0.f;
#pragma unroll
    for (int v8 = 0; v8 < 8; v8++) O[hh][v8] = (f32x4){0.f, 0.f, 0.f, 0.f};
  }

  short* Pw = Pbuf + w * 16 * PSTR;
  const float scale = 0.08838834764831844f;

  // per-lane swizzled read-column tables (constant across tiles)
  const int x7 = l16 & 7;
  int kcol[4], vcol[2];
#pragma unroll
  for (int kc = 0; kc < 4; kc++) kcol[kc] = ((kc * 4 + quad) ^ x7) * 8;
#pragma unroll
  for (int ks = 0; ks < 2; ks++) vcol[ks] = ((ks * 4 + quad) ^ x7) * 8;

  for (int st = 0; st <= qt; st++) {
    const int s0 = st * 64;
    const int dmin_s = doc_ids[b * TT + s0];
    const int dmax_s = doc_ids[b * TT + s0 + 63];
    if (dmax_s < docmin_q) continue;
    const bool full = (st < qt) && (dmin_s == docmax_q);

    __syncthreads();
    // K: 16 KB = 16 x 1KB issues, 4 per wave; source chunk pre-XOR'd.
#pragma unroll
    for (int j = 0; j < 4; j++) {
      const int f = w * 4 + j;
      const int rg = f * 4 + (lane >> 4);
      GLD16(qkv + (size_t)(b * TT + s0 + rg) * QKV_N + KOFF
                + (((lane & 15) ^ (rg & 7)) * 8),
            Ks + f * 512);
    }
    // V: 16 KB = 16 x 1KB issues, 4 per wave.
#pragma unroll
    for (int j = 0; j < 4; j++) {
      const int f = w * 4 + j;
      const int n = f * 8 + (lane >> 3);
      GLD16(Vtb + (((size_t)(b * 128 + n)) << 11) + s0
                + (((lane & 7) ^ (lane >> 3)) * 8),
            Vt + f * 512);
    }
    if (!full && tid < 64) doc_s[tid] = doc_ids[b * TT + s0 + tid];
    __syncthreads();   // drains vmcnt: staging landed

#pragma unroll
    for (int hh = 0; hh < 2; hh++) {
      f32x4 S[4];
#pragma unroll
      for (int ns = 0; ns < 4; ns++) {
        f32x4 acc = (f32x4){0.f, 0.f, 0.f, 0.f};
        const short* krow = Ks + (ns * 16 + l16) * 128;
#pragma unroll
        for (int kc = 0; kc < 4; kc++) {
          short8 kf = *(const short8*)(krow + kcol[kc]);
          acc = __builtin_amdgcn_mfma_f32_16x16x32_bf16(Qf[hh][kc], kf, acc, 0, 0, 0);
        }
        S[ns] = acc;
      }

      if (full) {
#pragma unroll
        for (int ns = 0; ns < 4; ns++)
#pragma unroll
          for (int r = 0; r < 4; r++) {
            const float p = __expf(S[ns][r] * scale);
            l_i[hh][r] += p;
            Pw[(quad * 4 + r) * PSTR + ns * 16 + l16] = f2bf(p);
          }
      } else {
#pragma unroll
        for (int ns = 0; ns < 4; ns++) {
          const int s_loc = ns * 16 + l16;
          const int sg = s0 + s_loc;
          const int sdoc = doc_s[s_loc];
#pragma unroll
          for (int r = 0; r < 4; r++) {
            const bool ok = (sg <= qg[r]) && (sdoc == mydoc[r]);
            const float p = ok ? __expf(S[ns][r] * scale) : 0.f;
            l_i[hh][r] += p;
            Pw[(quad * 4 + r) * PSTR + ns * 16 + l16] = f2bf(p);
          }
        }
      }

#pragma unroll
      for (int ks = 0; ks < 2; ks++) {
        short8 pf = *(const short8*)(Pw + l16 * PSTR + ks * 32 + quad * 8);
#pragma unroll
        for (int v8 = 0; v8 < 8; v8++) {
          short8 vf = *(const short8*)(Vt + (v8 * 16 + l16) * 64 + vcol[ks]);
          O[hh][v8] = __builtin_amdgcn_mfma_f32_16x16x32_bf16(pf, vf, O[hh][v8], 0, 0, 0);
        }
      }
    }  // hh
  }

#pragma unroll
  for (int hh = 0; hh < 2; hh++) {
#pragma unroll
    for (int off = 8; off >= 1; off >>= 1)
#pragma unroll
      for (int r = 0; r < 4; r++) l_i[hh][r] += __shfl_xor(l_i[hh][r], off);

#pragma unroll
    for (int r = 0; r < 4; r++) {
      const float inv = 1.f / l_i[hh][r];
      short* op = attn_out + (size_t)(b * TT + qg[r]) * D_MODEL
                  + (h0 + hh) * HEAD_DIM + l16;
#pragma unroll
      for (int v8 = 0; v8 < 8; v8++)
        op[v8 * 16] = f2bf(O[hh][v8][r] * inv);
    }
  }
}

// ---------------------------------------------------------------------------
extern "C" void kernel_launch(void* const* d_in, const int* in_sizes, int n_in,
                              void* d_out, int out_size, void* d_ws, size_t ws_size,
                              hipStream_t stream)
{
  const float* x     = (const float*)d_in[0];
  const float* sin_t = (const float*)d_in[1];
  const float* cos_t = (const float*)d_in[2];
  const int*   doc   = (const int*)  d_in[3];
  const float* W_qkv = (const float*)d_in[4];
  const float* W_out = (const float*)d_in[5];
  float* out = (float*)d_out;

  const int M = BB * TT;  // 4096

  char* p = (char*)d_ws;
  short* qkv_bf = (short*)p; p += (size_t)M * QKV_N * 2;
  short* xb     = (short*)p; p += (size_t)M * D_MODEL * 2;
  short* attn_bf = xb;  // alias: xb dead after GEMM1
  short* Vtb    = (short*)p; p += (size_t)BB * 128 * TT * 2;
  short* Wqkv_t = (short*)p; p += (size_t)QKV_N * D_MODEL * 2;
  short* Wout_t = (short*)p;

  // fused preps
  prep_all<<<XB_BLOCKS + WQ_BLOCKS + WO_BLOCKS, 256, 0, stream>>>(
      x, xb, W_qkv, Wqkv_t, W_out, Wout_t);

  // GEMM1 fused with RoPE + V-transpose epilogue (BK=64, 2-barrier)
  {
    dim3 grid(QKV_N / 128, M / 128);
    gemm_qkv_rope<<<grid, 256, 0, stream>>>(xb, Wqkv_t, qkv_bf, Vtb, sin_t, cos_t);
  }
  // flash attention (GLD16-staged K/V, 2 heads per block)
  {
    dim3 grid(TT / 64, NUM_HEADS / 2, BB);
    attn_mfma<<<grid, 256, 0, stream>>>(qkv_bf, Vtb, doc, attn_bf);
  }
  // GEMM2 (BK=64, 2-barrier)
  {
    dim3 grid(D_MODEL / 128, M / 128);
    gemm_mfma_bt<<<grid, 256, 0, stream>>>(attn_bf, Wout_t, out, M, D_MODEL, D_MODEL);
  }
}

// Round 9
// 258.934 us; speedup vs baseline: 1.0558x; 1.0558x over previous
//
#include <hip/hip_runtime.h>
#include <math.h>

#define D_MODEL 2048
#define NUM_HEADS 16
#define HEAD_DIM 128
#define BB 2
#define TT 2048
#define QKV_N 2304
#define KOFF 2048
#define VOFF 2176

typedef __attribute__((ext_vector_type(8))) short short8;
typedef __attribute__((ext_vector_type(4))) float f32x4;

static __device__ __forceinline__ short f2bf(float f) {
  union { float f; unsigned u; } x; x.f = f;
  unsigned r = (x.u + 0x7FFFu + ((x.u >> 16) & 1u)) >> 16;
  return (short)r;
}

#define GLD16(gp, lp)                                              \
  __builtin_amdgcn_global_load_lds(                                \
      (const __attribute__((address_space(1))) void*)(gp),         \
      (__attribute__((address_space(3))) void*)(lp), 16, 0, 0)

// 8-row-band column-major block swizzle: temporally adjacent blocks share an
// A band -> L2 locality (round 7: FETCH 89->46 MB).
static __device__ __forceinline__ void swizzle_xy(int& bx, int& by) {
  const int gx = gridDim.x;
  const int lin = blockIdx.y * gx + blockIdx.x;
  const int band = lin / (gx * 8);
  const int rem = lin - band * gx * 8;
  by = band * 8 + (rem & 7);
  bx = rem >> 3;
}

// ---------------------------------------------------------------------------
// GEMM1 fused: qkv = x @ W_qkv, RoPE in-epilogue, V written transposed.
// Round-0's 2-barrier BK=64 structure (68.5 us measured round 7, best of 4
// variants). Bank-conflict XOR swizzle kept (4.7M conflict cyc -> 0).
// ---------------------------------------------------------------------------
__global__ __launch_bounds__(256) void gemm_qkv_rope(
    const short* __restrict__ A, const short* __restrict__ Bt,
    short* __restrict__ qkv, short* __restrict__ Vtb,
    const float* __restrict__ sin_t, const float* __restrict__ cos_t)
{
  __shared__ short As[2 * 128 * 32];  // [kc][m][32], 16 KB
  __shared__ short Bs[2 * 128 * 32];  // [kc][n][32], 16 KB
  const int K = D_MODEL;

  int bx, by;
  swizzle_xy(bx, by);

  const int tid = threadIdx.x;
  const int w = tid >> 6, l = tid & 63;
  const int quad = l >> 4, l16 = l & 15;
  const int wm = w >> 1, wn = w & 1;
  const int m0 = by * 128, n0 = bx * 128;

  f32x4 acc[4][4];
#pragma unroll
  for (int i = 0; i < 4; i++)
#pragma unroll
    for (int j = 0; j < 4; j++) acc[i][j] = (f32x4){0.f, 0.f, 0.f, 0.f};

  const int cswz = ((l & 3) ^ ((l >> 3) & 3)) * 8;
  const short* aA = A + (size_t)(m0 + w * 32 + (l >> 2)) * K + cswz;
  const short* aB = Bt + (size_t)(n0 + w * 32 + (l >> 2)) * K + cswz;
  short* lA = As + w * 1024;  // wave-uniform LDS bases
  short* lB = Bs + w * 1024;

  const int aswz = (quad ^ ((l16 >> 1) & 3)) * 8;
  const short* Ard = As + (size_t)(wm * 64 + l16) * 32 + aswz;
  const short* Brd = Bs + (size_t)(wn * 16 + l16) * 32 + aswz;

  for (int k0 = 0; k0 < K; k0 += 64) {
    __syncthreads();
#pragma unroll
    for (int h = 0; h < 2; h++) {  // two 32-k panels
      const int go = k0 + h * 32;
      const int lo = h * 4096;
      GLD16(aA + go, lA + lo);
      GLD16(aA + go + (size_t)16 * K, lA + lo + 512);
      GLD16(aB + go, lB + lo);
      GLD16(aB + go + (size_t)16 * K, lB + lo + 512);
    }
    __syncthreads();

#pragma unroll
    for (int kc = 0; kc < 2; kc++) {
      short8 af[4], bf[4];
#pragma unroll
      for (int mi = 0; mi < 4; mi++)
        af[mi] = *(const short8*)(Ard + kc * 4096 + mi * 512);
#pragma unroll
      for (int ni = 0; ni < 4; ni++)
        bf[ni] = *(const short8*)(Brd + kc * 4096 + ni * 1024);
#pragma unroll
      for (int mi = 0; mi < 4; mi++)
#pragma unroll
        for (int ni = 0; ni < 4; ni++)
          acc[mi][ni] =
              __builtin_amdgcn_mfma_f32_16x16x32_bf16(af[mi], bf[ni], acc[mi][ni], 0, 0, 0);
    }
  }

  const int colbase = wn * 16 + l16;      // in [0,32)
  const bool is_v = (n0 == VOFF);         // V head: no rope, transposed out

#pragma unroll
  for (int mi = 0; mi < 4; mi++) {
#pragma unroll
    for (int r = 0; r < 4; r++) {
      const int row = m0 + wm * 64 + mi * 16 + quad * 4 + r;
      const int b = row >> 11, t = row & (TT - 1);
#pragma unroll
      for (int ni = 0; ni < 2; ni++) {
        const int cloc = ni * 32 + colbase;   // in [0,64)
        const float c1 = acc[mi][ni][r];
        const float c2 = acc[mi][ni + 2][r];
        if (!is_v) {
          const float sn = sin_t[t * 64 + cloc];
          const float cs = cos_t[t * 64 + cloc];
          short* op = qkv + (size_t)row * QKV_N + n0 + cloc;
          op[0]  = f2bf(c1 * cs - c2 * sn);
          op[64] = f2bf(c2 * cs + c1 * sn);
        } else {
          Vtb[((size_t)(b * 128 + cloc) << 11) + t]      = f2bf(c1);
          Vtb[((size_t)(b * 128 + cloc + 64) << 11) + t] = f2bf(c2);
        }
      }
    }
  }
}

// ---------------------------------------------------------------------------
// GEMM2: out = attn_bf @ Wout_t^T, fp32 out. Round-0 BK=64 2-barrier + swizzle.
// ---------------------------------------------------------------------------
__global__ __launch_bounds__(256) void gemm_mfma_bt(
    const short* __restrict__ A, const short* __restrict__ Bt,
    float* __restrict__ C, int M, int N, int K)
{
  __shared__ short As[2 * 128 * 32];
  __shared__ short Bs[2 * 128 * 32];

  int bx, by;
  swizzle_xy(bx, by);

  const int tid = threadIdx.x;
  const int w = tid >> 6, l = tid & 63;
  const int quad = l >> 4, l16 = l & 15;
  const int wm = w >> 1, wn = w & 1;
  const int m0 = by * 128, n0 = bx * 128;

  f32x4 acc[4][4];
#pragma unroll
  for (int i = 0; i < 4; i++)
#pragma unroll
    for (int j = 0; j < 4; j++) acc[i][j] = (f32x4){0.f, 0.f, 0.f, 0.f};

  const int cswz = ((l & 3) ^ ((l >> 3) & 3)) * 8;
  const short* aA = A + (size_t)(m0 + w * 32 + (l >> 2)) * K + cswz;
  const short* aB = Bt + (size_t)(n0 + w * 32 + (l >> 2)) * K + cswz;
  short* lA = As + w * 1024;
  short* lB = Bs + w * 1024;

  const int aswz = (quad ^ ((l16 >> 1) & 3)) * 8;
  const short* Ard = As + (size_t)(wm * 64 + l16) * 32 + aswz;
  const short* Brd = Bs + (size_t)(wn * 64 + l16) * 32 + aswz;

  for (int k0 = 0; k0 < K; k0 += 64) {
    __syncthreads();
#pragma unroll
    for (int h = 0; h < 2; h++) {
      const int go = k0 + h * 32;
      const int lo = h * 4096;
      GLD16(aA + go, lA + lo);
      GLD16(aA + go + (size_t)16 * K, lA + lo + 512);
      GLD16(aB + go, lB + lo);
      GLD16(aB + go + (size_t)16 * K, lB + lo + 512);
    }
    __syncthreads();

#pragma unroll
    for (int kc = 0; kc < 2; kc++) {
      short8 af[4], bf[4];
#pragma unroll
      for (int mi = 0; mi < 4; mi++)
        af[mi] = *(const short8*)(Ard + kc * 4096 + mi * 512);
#pragma unroll
      for (int ni = 0; ni < 4; ni++)
        bf[ni] = *(const short8*)(Brd + kc * 4096 + ni * 512);
#pragma unroll
      for (int mi = 0; mi < 4; mi++)
#pragma unroll
        for (int ni = 0; ni < 4; ni++)
          acc[mi][ni] =
              __builtin_amdgcn_mfma_f32_16x16x32_bf16(af[mi], bf[ni], acc[mi][ni], 0, 0, 0);
    }
  }

#pragma unroll
  for (int mi = 0; mi < 4; mi++) {
#pragma unroll
    for (int ni = 0; ni < 4; ni++) {
#pragma unroll
      for (int r = 0; r < 4; r++) {
        const int row = m0 + wm * 64 + mi * 16 + quad * 4 + r;
        const int col = n0 + wn * 64 + ni * 16 + l16;
        C[(size_t)row * N + col] = acc[mi][ni][r];
      }
    }
  }
}

// ---------------------------------------------------------------------------
// Fused prep: convert x -> bf16, transpose+convert W_qkv and W_out.
// ---------------------------------------------------------------------------
#define XB_BLOCKS 8192                 // 4096*2048/4/256
#define WQ_BLOCKS (72 * 64)            // (2304/32)*(2048/32)
#define WO_BLOCKS (64 * 64)

__global__ __launch_bounds__(256) void prep_all(
    const float* __restrict__ x, short* __restrict__ xb,
    const float* __restrict__ Wq, short* __restrict__ Wqt,
    const float* __restrict__ Wo, short* __restrict__ Wot)
{
  const int bid = blockIdx.x;
  const int tid = threadIdx.x;

  if (bid < XB_BLOCKS) {
    const size_t i4 = (size_t)bid * 256 + tid;
    float4 v = *(const float4*)(x + i4 * 4);
    short4 o;
    o.x = f2bf(v.x); o.y = f2bf(v.y); o.z = f2bf(v.z); o.w = f2bf(v.w);
    *(short4*)(xb + i4 * 4) = o;
    return;
  }

  __shared__ float t[32][33];
  const float* W;
  short* Wt;
  int N, tile, ntx;
  if (bid < XB_BLOCKS + WQ_BLOCKS) {
    tile = bid - XB_BLOCKS; W = Wq; Wt = Wqt; N = QKV_N; ntx = 72;
  } else {
    tile = bid - XB_BLOCKS - WQ_BLOCKS; W = Wo; Wt = Wot; N = D_MODEL; ntx = 64;
  }
  const int K = D_MODEL;
  const int bx = tile % ntx, byy = tile / ntx;
  const int tx = tid & 31, ty = tid >> 5;
  const int n0 = bx * 32, k0 = byy * 32;
#pragma unroll
  for (int j = 0; j < 4; j++)
    t[ty + j * 8][tx] = W[(size_t)(k0 + ty + j * 8) * N + n0 + tx];
  __syncthreads();
#pragma unroll
  for (int j = 0; j < 4; j++)
    Wt[(size_t)(n0 + ty + j * 8) * K + k0 + tx] = f2bf(t[tx][ty + j * 8]);
}

// ---------------------------------------------------------------------------
// Flash MQA attention, round 9: complementary q-tile pairing on the round-7
// GLD16+XOR structure. Block x handles q-tiles (x, 31-x):
//  - compute per block = (x+1)+(32-x) = 33 tiles, CONSTANT -> no causal
//    straggler tail (round-8 lesson: 2 blocks/CU can't smooth imbalance).
//  - shared K/V staging over the union range st=0..31-x: staged tiles per
//    (h,b) drop 528 -> 392 (-26%); low-st tiles amortize one stage across
//    two QK+PV clusters.
// Grid (16,16,2) = 512 = 2.0/CU (LDS 45KB allows 3 -> overlap preserved).
// __launch_bounds__(256,2): ~160 live VGPR, budget 256 (round-5 lesson).
// ---------------------------------------------------------------------------
#define PSTR 72

__global__ __launch_bounds__(256, 2) void attn_mfma(
    const short* __restrict__ qkv, const short* __restrict__ Vtb,
    const int* __restrict__ doc_ids, short* __restrict__ attn_out)
{
  __shared__ short Ks[64 * 128];     // 16 KB, linear + chunk-XOR
  __shared__ short Vt[128 * 64];     // 16 KB, linear + chunk-XOR
  __shared__ short Pbuf[4 * 16 * PSTR];
  __shared__ int doc_s[64];

  const int h = blockIdx.y, b = blockIdx.z;
  const int qt0 = blockIdx.x;        // 0..15
  const int qt1 = 31 - qt0;          // 16..31
  const int tid = threadIdx.x;
  const int w = tid >> 6;
  const int lane = tid & 63;
  const int quad = lane >> 4, l16 = lane & 15;

  short8 Qf[2][4];
  int qg[2][4], mydoc[2][4];
  float l_i[2][4];
  f32x4 O[2][8];
  int docmin[2], docmax[2];

#pragma unroll
  for (int qi = 0; qi < 2; qi++) {
    const int q0 = (qi ? qt1 : qt0) * 64;
    const short* qp = qkv + (size_t)(b * TT + q0 + w * 16 + l16) * QKV_N
                      + h * HEAD_DIM + quad * 8;
#pragma unroll
    for (int kc = 0; kc < 4; kc++) Qf[qi][kc] = *(const short8*)(qp + kc * 32);
    docmin[qi] = doc_ids[b * TT + q0];
    docmax[qi] = doc_ids[b * TT + q0 + 63];
#pragma unroll
    for (int r = 0; r < 4; r++) {
      qg[qi][r] = q0 + w * 16 + quad * 4 + r;
      mydoc[qi][r] = doc_ids[b * TT + qg[qi][r]];
      l_i[qi][r] = 0.f;
    }
#pragma unroll
    for (int v8 = 0; v8 < 8; v8++) O[qi][v8] = (f32x4){0.f, 0.f, 0.f, 0.f};
  }

  short* Pw = Pbuf + w * 16 * PSTR;
  const float scale = 0.08838834764831844f;

  // per-lane swizzled read-column tables (constant across tiles)
  const int x7 = l16 & 7;
  int kcol[4], vcol[2];
#pragma unroll
  for (int kc = 0; kc < 4; kc++) kcol[kc] = ((kc * 4 + quad) ^ x7) * 8;
#pragma unroll
  for (int ks = 0; ks < 2; ks++) vcol[ks] = ((ks * 4 + quad) ^ x7) * 8;

  for (int st = 0; st <= qt1; st++) {
    const int s0 = st * 64;
    const int dmin_s = doc_ids[b * TT + s0];
    const int dmax_s = doc_ids[b * TT + s0 + 63];
    const bool act0 = (st <= qt0) && (dmax_s >= docmin[0]);
    const bool act1 = (dmax_s >= docmin[1]);
    if (!act0 && !act1) continue;            // block-uniform
    const bool full0 = (st < qt0) && (dmin_s == docmax[0]);
    const bool full1 = (st < qt1) && (dmin_s == docmax[1]);
    const bool needdoc = (act0 && !full0) || (act1 && !full1);

    __syncthreads();
    // K: 16 KB = 16 x 1KB issues, 4 per wave; source chunk pre-XOR'd.
#pragma unroll
    for (int j = 0; j < 4; j++) {
      const int f = w * 4 + j;
      const int rg = f * 4 + (lane >> 4);
      GLD16(qkv + (size_t)(b * TT + s0 + rg) * QKV_N + KOFF
                + (((lane & 15) ^ (rg & 7)) * 8),
            Ks + f * 512);
    }
    // V: 16 KB = 16 x 1KB issues, 4 per wave.
#pragma unroll
    for (int j = 0; j < 4; j++) {
      const int f = w * 4 + j;
      const int n = f * 8 + (lane >> 3);
      GLD16(Vtb + (((size_t)(b * 128 + n)) << 11) + s0
                + (((lane & 7) ^ (lane >> 3)) * 8),
            Vt + f * 512);
    }
    if (needdoc && tid < 64) doc_s[tid] = doc_ids[b * TT + s0 + tid];
    __syncthreads();   // drains vmcnt: staging landed

#pragma unroll
    for (int qi = 0; qi < 2; qi++) {
      const bool act = qi ? act1 : act0;
      if (!act) continue;
      const bool full = qi ? full1 : full0;

      f32x4 S[4];
#pragma unroll
      for (int ns = 0; ns < 4; ns++) {
        f32x4 acc = (f32x4){0.f, 0.f, 0.f, 0.f};
        const short* krow = Ks + (ns * 16 + l16) * 128;
#pragma unroll
        for (int kc = 0; kc < 4; kc++) {
          short8 kf = *(const short8*)(krow + kcol[kc]);
          acc = __builtin_amdgcn_mfma_f32_16x16x32_bf16(Qf[qi][kc], kf, acc, 0, 0, 0);
        }
        S[ns] = acc;
      }

      if (full) {
#pragma unroll
        for (int ns = 0; ns < 4; ns++)
#pragma unroll
          for (int r = 0; r < 4; r++) {
            const float p = __expf(S[ns][r] * scale);
            l_i[qi][r] += p;
            Pw[(quad * 4 + r) * PSTR + ns * 16 + l16] = f2bf(p);
          }
      } else {
#pragma unroll
        for (int ns = 0; ns < 4; ns++) {
          const int s_loc = ns * 16 + l16;
          const int sg = s0 + s_loc;
          const int sdoc = doc_s[s_loc];
#pragma unroll
          for (int r = 0; r < 4; r++) {
            const bool ok = (sg <= qg[qi][r]) && (sdoc == mydoc[qi][r]);
            const float p = ok ? __expf(S[ns][r] * scale) : 0.f;
            l_i[qi][r] += p;
            Pw[(quad * 4 + r) * PSTR + ns * 16 + l16] = f2bf(p);
          }
        }
      }

#pragma unroll
      for (int ks = 0; ks < 2; ks++) {
        short8 pf = *(const short8*)(Pw + l16 * PSTR + ks * 32 + quad * 8);
#pragma unroll
        for (int v8 = 0; v8 < 8; v8++) {
          short8 vf = *(const short8*)(Vt + (v8 * 16 + l16) * 64 + vcol[ks]);
          O[qi][v8] = __builtin_amdgcn_mfma_f32_16x16x32_bf16(pf, vf, O[qi][v8], 0, 0, 0);
        }
      }
    }  // qi
  }

#pragma unroll
  for (int qi = 0; qi < 2; qi++) {
#pragma unroll
    for (int off = 8; off >= 1; off >>= 1)
#pragma unroll
      for (int r = 0; r < 4; r++) l_i[qi][r] += __shfl_xor(l_i[qi][r], off);

#pragma unroll
    for (int r = 0; r < 4; r++) {
      const float inv = 1.f / l_i[qi][r];
      short* op = attn_out + (size_t)(b * TT + qg[qi][r]) * D_MODEL
                  + h * HEAD_DIM + l16;
#pragma unroll
      for (int v8 = 0; v8 < 8; v8++)
        op[v8 * 16] = f2bf(O[qi][v8][r] * inv);
    }
  }
}

// ---------------------------------------------------------------------------
extern "C" void kernel_launch(void* const* d_in, const int* in_sizes, int n_in,
                              void* d_out, int out_size, void* d_ws, size_t ws_size,
                              hipStream_t stream)
{
  const float* x     = (const float*)d_in[0];
  const float* sin_t = (const float*)d_in[1];
  const float* cos_t = (const float*)d_in[2];
  const int*   doc   = (const int*)  d_in[3];
  const float* W_qkv = (const float*)d_in[4];
  const float* W_out = (const float*)d_in[5];
  float* out = (float*)d_out;

  const int M = BB * TT;  // 4096

  char* p = (char*)d_ws;
  short* qkv_bf = (short*)p; p += (size_t)M * QKV_N * 2;
  short* xb     = (short*)p; p += (size_t)M * D_MODEL * 2;
  short* attn_bf = xb;  // alias: xb dead after GEMM1
  short* Vtb    = (short*)p; p += (size_t)BB * 128 * TT * 2;
  short* Wqkv_t = (short*)p; p += (size_t)QKV_N * D_MODEL * 2;
  short* Wout_t = (short*)p;

  // fused preps
  prep_all<<<XB_BLOCKS + WQ_BLOCKS + WO_BLOCKS, 256, 0, stream>>>(
      x, xb, W_qkv, Wqkv_t, W_out, Wout_t);

  // GEMM1 fused with RoPE + V-transpose epilogue (BK=64, 2-barrier)
  {
    dim3 grid(QKV_N / 128, M / 128);
    gemm_qkv_rope<<<grid, 256, 0, stream>>>(xb, Wqkv_t, qkv_bf, Vtb, sin_t, cos_t);
  }
  // flash attention (paired q-tiles, shared staging)
  {
    dim3 grid(TT / 128, NUM_HEADS, BB);   // 16 paired q-tile blocks
    attn_mfma<<<grid, 256, 0, stream>>>(qkv_bf, Vtb, doc, attn_bf);
  }
  // GEMM2 (BK=64, 2-barrier)
  {
    dim3 grid(D_MODEL / 128, M / 128);
    gemm_mfma_bt<<<grid, 256, 0, stream>>>(attn_bf, Wout_t, out, M, D_MODEL, D_MODEL);
  }
}

// Round 10
// 256.785 us; speedup vs baseline: 1.0646x; 1.0084x over previous
//
#include <hip/hip_runtime.h>
#include <math.h>

#define D_MODEL 2048
#define NUM_HEADS 16
#define HEAD_DIM 128
#define BB 2
#define TT 2048
#define QKV_N 2304
#define KOFF 2048
#define VOFF 2176

typedef __attribute__((ext_vector_type(8))) short short8;
typedef __attribute__((ext_vector_type(4))) float f32x4;

static __device__ __forceinline__ short f2bf(float f) {
  union { float f; unsigned u; } x; x.f = f;
  unsigned r = (x.u + 0x7FFFu + ((x.u >> 16) & 1u)) >> 16;
  return (short)r;
}

#define GLD16(gp, lp)                                              \
  __builtin_amdgcn_global_load_lds(                                \
      (const __attribute__((address_space(1))) void*)(gp),         \
      (__attribute__((address_space(3))) void*)(lp), 16, 0, 0)

// 8-row-band column-major block swizzle: temporally adjacent blocks share an
// A band -> L2 locality (round 7: FETCH 89->46 MB).
static __device__ __forceinline__ void swizzle_xy(int& bx, int& by) {
  const int gx = gridDim.x;
  const int lin = blockIdx.y * gx + blockIdx.x;
  const int band = lin / (gx * 8);
  const int rem = lin - band * gx * 8;
  by = band * 8 + (rem & 7);
  bx = rem >> 3;
}

// ---------------------------------------------------------------------------
// GEMM1 fused: qkv = x @ W_qkv, RoPE in-epilogue, V written transposed.
// Round-0's 2-barrier BK=64 structure (68.5 us measured round 7, best of 4
// variants). Bank-conflict XOR swizzle kept (4.7M conflict cyc -> 0).
// ---------------------------------------------------------------------------
__global__ __launch_bounds__(256) void gemm_qkv_rope(
    const short* __restrict__ A, const short* __restrict__ Bt,
    short* __restrict__ qkv, short* __restrict__ Vtb,
    const float* __restrict__ sin_t, const float* __restrict__ cos_t)
{
  __shared__ short As[2 * 128 * 32];  // [kc][m][32], 16 KB
  __shared__ short Bs[2 * 128 * 32];  // [kc][n][32], 16 KB
  const int K = D_MODEL;

  int bx, by;
  swizzle_xy(bx, by);

  const int tid = threadIdx.x;
  const int w = tid >> 6, l = tid & 63;
  const int quad = l >> 4, l16 = l & 15;
  const int wm = w >> 1, wn = w & 1;
  const int m0 = by * 128, n0 = bx * 128;

  f32x4 acc[4][4];
#pragma unroll
  for (int i = 0; i < 4; i++)
#pragma unroll
    for (int j = 0; j < 4; j++) acc[i][j] = (f32x4){0.f, 0.f, 0.f, 0.f};

  const int cswz = ((l & 3) ^ ((l >> 3) & 3)) * 8;
  const short* aA = A + (size_t)(m0 + w * 32 + (l >> 2)) * K + cswz;
  const short* aB = Bt + (size_t)(n0 + w * 32 + (l >> 2)) * K + cswz;
  short* lA = As + w * 1024;  // wave-uniform LDS bases
  short* lB = Bs + w * 1024;

  const int aswz = (quad ^ ((l16 >> 1) & 3)) * 8;
  const short* Ard = As + (size_t)(wm * 64 + l16) * 32 + aswz;
  const short* Brd = Bs + (size_t)(wn * 16 + l16) * 32 + aswz;

  for (int k0 = 0; k0 < K; k0 += 64) {
    __syncthreads();
#pragma unroll
    for (int h = 0; h < 2; h++) {  // two 32-k panels
      const int go = k0 + h * 32;
      const int lo = h * 4096;
      GLD16(aA + go, lA + lo);
      GLD16(aA + go + (size_t)16 * K, lA + lo + 512);
      GLD16(aB + go, lB + lo);
      GLD16(aB + go + (size_t)16 * K, lB + lo + 512);
    }
    __syncthreads();

#pragma unroll
    for (int kc = 0; kc < 2; kc++) {
      short8 af[4], bf[4];
#pragma unroll
      for (int mi = 0; mi < 4; mi++)
        af[mi] = *(const short8*)(Ard + kc * 4096 + mi * 512);
#pragma unroll
      for (int ni = 0; ni < 4; ni++)
        bf[ni] = *(const short8*)(Brd + kc * 4096 + ni * 1024);
#pragma unroll
      for (int mi = 0; mi < 4; mi++)
#pragma unroll
        for (int ni = 0; ni < 4; ni++)
          acc[mi][ni] =
              __builtin_amdgcn_mfma_f32_16x16x32_bf16(af[mi], bf[ni], acc[mi][ni], 0, 0, 0);
    }
  }

  const int colbase = wn * 16 + l16;      // in [0,32)
  const bool is_v = (n0 == VOFF);         // V head: no rope, transposed out

#pragma unroll
  for (int mi = 0; mi < 4; mi++) {
#pragma unroll
    for (int r = 0; r < 4; r++) {
      const int row = m0 + wm * 64 + mi * 16 + quad * 4 + r;
      const int b = row >> 11, t = row & (TT - 1);
#pragma unroll
      for (int ni = 0; ni < 2; ni++) {
        const int cloc = ni * 32 + colbase;   // in [0,64)
        const float c1 = acc[mi][ni][r];
        const float c2 = acc[mi][ni + 2][r];
        if (!is_v) {
          const float sn = sin_t[t * 64 + cloc];
          const float cs = cos_t[t * 64 + cloc];
          short* op = qkv + (size_t)row * QKV_N + n0 + cloc;
          op[0]  = f2bf(c1 * cs - c2 * sn);
          op[64] = f2bf(c2 * cs + c1 * sn);
        } else {
          Vtb[((size_t)(b * 128 + cloc) << 11) + t]      = f2bf(c1);
          Vtb[((size_t)(b * 128 + cloc + 64) << 11) + t] = f2bf(c2);
        }
      }
    }
  }
}

// ---------------------------------------------------------------------------
// GEMM2: out = attn_bf @ Wout_t^T, fp32 out. Round-0 BK=64 2-barrier + swizzle.
// ---------------------------------------------------------------------------
__global__ __launch_bounds__(256) void gemm_mfma_bt(
    const short* __restrict__ A, const short* __restrict__ Bt,
    float* __restrict__ C, int M, int N, int K)
{
  __shared__ short As[2 * 128 * 32];
  __shared__ short Bs[2 * 128 * 32];

  int bx, by;
  swizzle_xy(bx, by);

  const int tid = threadIdx.x;
  const int w = tid >> 6, l = tid & 63;
  const int quad = l >> 4, l16 = l & 15;
  const int wm = w >> 1, wn = w & 1;
  const int m0 = by * 128, n0 = bx * 128;

  f32x4 acc[4][4];
#pragma unroll
  for (int i = 0; i < 4; i++)
#pragma unroll
    for (int j = 0; j < 4; j++) acc[i][j] = (f32x4){0.f, 0.f, 0.f, 0.f};

  const int cswz = ((l & 3) ^ ((l >> 3) & 3)) * 8;
  const short* aA = A + (size_t)(m0 + w * 32 + (l >> 2)) * K + cswz;
  const short* aB = Bt + (size_t)(n0 + w * 32 + (l >> 2)) * K + cswz;
  short* lA = As + w * 1024;
  short* lB = Bs + w * 1024;

  const int aswz = (quad ^ ((l16 >> 1) & 3)) * 8;
  const short* Ard = As + (size_t)(wm * 64 + l16) * 32 + aswz;
  const short* Brd = Bs + (size_t)(wn * 64 + l16) * 32 + aswz;

  for (int k0 = 0; k0 < K; k0 += 64) {
    __syncthreads();
#pragma unroll
    for (int h = 0; h < 2; h++) {
      const int go = k0 + h * 32;
      const int lo = h * 4096;
      GLD16(aA + go, lA + lo);
      GLD16(aA + go + (size_t)16 * K, lA + lo + 512);
      GLD16(aB + go, lB + lo);
      GLD16(aB + go + (size_t)16 * K, lB + lo + 512);
    }
    __syncthreads();

#pragma unroll
    for (int kc = 0; kc < 2; kc++) {
      short8 af[4], bf[4];
#pragma unroll
      for (int mi = 0; mi < 4; mi++)
        af[mi] = *(const short8*)(Ard + kc * 4096 + mi * 512);
#pragma unroll
      for (int ni = 0; ni < 4; ni++)
        bf[ni] = *(const short8*)(Brd + kc * 4096 + ni * 512);
#pragma unroll
      for (int mi = 0; mi < 4; mi++)
#pragma unroll
        for (int ni = 0; ni < 4; ni++)
          acc[mi][ni] =
              __builtin_amdgcn_mfma_f32_16x16x32_bf16(af[mi], bf[ni], acc[mi][ni], 0, 0, 0);
    }
  }

#pragma unroll
  for (int mi = 0; mi < 4; mi++) {
#pragma unroll
    for (int ni = 0; ni < 4; ni++) {
#pragma unroll
      for (int r = 0; r < 4; r++) {
        const int row = m0 + wm * 64 + mi * 16 + quad * 4 + r;
        const int col = n0 + wn * 64 + ni * 16 + l16;
        C[(size_t)row * N + col] = acc[mi][ni][r];
      }
    }
  }
}

// ---------------------------------------------------------------------------
// Fused prep, round 10: both halves rebuilt for BW (prep was the unmodeled
// ~50us in the budget: 1 float4/thread x-conv had no ILP; 32x32 transposes
// wrote 64B segments from 8704 micro-blocks).
//  - x-conv: 2048 blocks grid-stride, 4 independent float4/thread.
//  - transpose: 64x64 tiles, float4 reads (256B/row), short8 writes (128B
//    segments), f32 LDS with XOR swizzle col^=(k&7)<<3: write <=2-way
//    (free, m136), read conflict-free ((ks+s)&7==s -> bank=n^(s<<3), a
//    lane permutation).
// ---------------------------------------------------------------------------
#define XC_BLOCKS 2048                 // 2048*256*4 float4 = 4096*2048 floats
#define WQT_TILES (36 * 32)            // (2304/64)*(2048/64)
#define WOT_TILES (32 * 32)            // (2048/64)*(2048/64)

__global__ __launch_bounds__(256) void prep_all(
    const float* __restrict__ x, short* __restrict__ xb,
    const float* __restrict__ Wq, short* __restrict__ Wqt,
    const float* __restrict__ Wo, short* __restrict__ Wot)
{
  const int bid = blockIdx.x;
  const int tid = threadIdx.x;

  if (bid < XC_BLOCKS) {
    const float4* xin = (const float4*)x;
    short4* xo = (short4*)xb;
    const size_t i0 = (size_t)bid * 256 + tid;
#pragma unroll
    for (int p = 0; p < 4; p++) {
      float4 v = xin[i0 + (size_t)p * 524288];
      short4 o;
      o.x = f2bf(v.x); o.y = f2bf(v.y); o.z = f2bf(v.z); o.w = f2bf(v.w);
      xo[i0 + (size_t)p * 524288] = o;
    }
    return;
  }

  __shared__ float t[64 * 64];         // 16 KB, XOR-swizzled
  int tile = bid - XC_BLOCKS;
  const float* W;
  short* Wt;
  int N, ntx;
  if (tile < WQT_TILES) {
    W = Wq; Wt = Wqt; N = QKV_N; ntx = 36;
  } else {
    tile -= WQT_TILES; W = Wo; Wt = Wot; N = D_MODEL; ntx = 32;
  }
  const int K = D_MODEL;
  const int n0 = (tile % ntx) * 64, k0 = (tile / ntx) * 64;

  // read-in: 4 passes x 16 rows; 16 lanes x float4 = 256B per row
  {
    const int kl = tid >> 4;           // 0..15
    const int c4 = (tid & 15) * 4;     // word col
#pragma unroll
    for (int j = 0; j < 4; j++) {
      const int kr = kl + j * 16;
      float4 v = *(const float4*)(W + (size_t)(k0 + kr) * N + n0 + c4);
      *(float4*)(t + kr * 64 + (c4 ^ ((kr & 7) << 3))) = v;
    }
  }
  __syncthreads();
  // read-out: 2 passes x 32 out-rows; 8 lanes x short8 = 128B per row
  {
    const int ks = (tid & 7) * 8;
#pragma unroll
    for (int j = 0; j < 2; j++) {
      const int nl = (tid >> 3) + j * 32;
      short8 o;
#pragma unroll
      for (int s = 0; s < 8; s++)
        o[s] = f2bf(t[(ks + s) * 64 + (nl ^ (s << 3))]);
      *(short8*)(Wt + (size_t)(n0 + nl) * K + k0 + ks) = o;
    }
  }
}

// ---------------------------------------------------------------------------
// Flash MQA attention, round 9 (verified 258.9us total): complementary
// q-tile pairing on the GLD16+XOR structure. Block x handles q-tiles
// (x, 31-x): constant 33-tile compute (no causal straggler), staging shared
// over the union range (528 -> 392 staged tiles). Grid (16,16,2) = 512 =
// 2.0/CU. __launch_bounds__(256,2) guards the allocator.
// ---------------------------------------------------------------------------
#define PSTR 72

__global__ __launch_bounds__(256, 2) void attn_mfma(
    const short* __restrict__ qkv, const short* __restrict__ Vtb,
    const int* __restrict__ doc_ids, short* __restrict__ attn_out)
{
  __shared__ short Ks[64 * 128];     // 16 KB, linear + chunk-XOR
  __shared__ short Vt[128 * 64];     // 16 KB, linear + chunk-XOR
  __shared__ short Pbuf[4 * 16 * PSTR];
  __shared__ int doc_s[64];

  const int h = blockIdx.y, b = blockIdx.z;
  const int qt0 = blockIdx.x;        // 0..15
  const int qt1 = 31 - qt0;          // 16..31
  const int tid = threadIdx.x;
  const int w = tid >> 6;
  const int lane = tid & 63;
  const int quad = lane >> 4, l16 = lane & 15;

  short8 Qf[2][4];
  int qg[2][4], mydoc[2][4];
  float l_i[2][4];
  f32x4 O[2][8];
  int docmin[2], docmax[2];

#pragma unroll
  for (int qi = 0; qi < 2; qi++) {
    const int q0 = (qi ? qt1 : qt0) * 64;
    const short* qp = qkv + (size_t)(b * TT + q0 + w * 16 + l16) * QKV_N
                      + h * HEAD_DIM + quad * 8;
#pragma unroll
    for (int kc = 0; kc < 4; kc++) Qf[qi][kc] = *(const short8*)(qp + kc * 32);
    docmin[qi] = doc_ids[b * TT + q0];
    docmax[qi] = doc_ids[b * TT + q0 + 63];
#pragma unroll
    for (int r = 0; r < 4; r++) {
      qg[qi][r] = q0 + w * 16 + quad * 4 + r;
      mydoc[qi][r] = doc_ids[b * TT + qg[qi][r]];
      l_i[qi][r] = 0.f;
    }
#pragma unroll
    for (int v8 = 0; v8 < 8; v8++) O[qi][v8] = (f32x4){0.f, 0.f, 0.f, 0.f};
  }

  short* Pw = Pbuf + w * 16 * PSTR;
  const float scale = 0.08838834764831844f;

  // per-lane swizzled read-column tables (constant across tiles)
  const int x7 = l16 & 7;
  int kcol[4], vcol[2];
#pragma unroll
  for (int kc = 0; kc < 4; kc++) kcol[kc] = ((kc * 4 + quad) ^ x7) * 8;
#pragma unroll
  for (int ks = 0; ks < 2; ks++) vcol[ks] = ((ks * 4 + quad) ^ x7) * 8;

  for (int st = 0; st <= qt1; st++) {
    const int s0 = st * 64;
    const int dmin_s = doc_ids[b * TT + s0];
    const int dmax_s = doc_ids[b * TT + s0 + 63];
    const bool act0 = (st <= qt0) && (dmax_s >= docmin[0]);
    const bool act1 = (dmax_s >= docmin[1]);
    if (!act0 && !act1) continue;            // block-uniform
    const bool full0 = (st < qt0) && (dmin_s == docmax[0]);
    const bool full1 = (st < qt1) && (dmin_s == docmax[1]);
    const bool needdoc = (act0 && !full0) || (act1 && !full1);

    __syncthreads();
    // K: 16 KB = 16 x 1KB issues, 4 per wave; source chunk pre-XOR'd.
#pragma unroll
    for (int j = 0; j < 4; j++) {
      const int f = w * 4 + j;
      const int rg = f * 4 + (lane >> 4);
      GLD16(qkv + (size_t)(b * TT + s0 + rg) * QKV_N + KOFF
                + (((lane & 15) ^ (rg & 7)) * 8),
            Ks + f * 512);
    }
    // V: 16 KB = 16 x 1KB issues, 4 per wave.
#pragma unroll
    for (int j = 0; j < 4; j++) {
      const int f = w * 4 + j;
      const int n = f * 8 + (lane >> 3);
      GLD16(Vtb + (((size_t)(b * 128 + n)) << 11) + s0
                + (((lane & 7) ^ (lane >> 3)) * 8),
            Vt + f * 512);
    }
    if (needdoc && tid < 64) doc_s[tid] = doc_ids[b * TT + s0 + tid];
    __syncthreads();   // drains vmcnt: staging landed

#pragma unroll
    for (int qi = 0; qi < 2; qi++) {
      const bool act = qi ? act1 : act0;
      if (!act) continue;
      const bool full = qi ? full1 : full0;

      f32x4 S[4];
#pragma unroll
      for (int ns = 0; ns < 4; ns++) {
        f32x4 acc = (f32x4){0.f, 0.f, 0.f, 0.f};
        const short* krow = Ks + (ns * 16 + l16) * 128;
#pragma unroll
        for (int kc = 0; kc < 4; kc++) {
          short8 kf = *(const short8*)(krow + kcol[kc]);
          acc = __builtin_amdgcn_mfma_f32_16x16x32_bf16(Qf[qi][kc], kf, acc, 0, 0, 0);
        }
        S[ns] = acc;
      }

      if (full) {
#pragma unroll
        for (int ns = 0; ns < 4; ns++)
#pragma unroll
          for (int r = 0; r < 4; r++) {
            const float p = __expf(S[ns][r] * scale);
            l_i[qi][r] += p;
            Pw[(quad * 4 + r) * PSTR + ns * 16 + l16] = f2bf(p);
          }
      } else {
#pragma unroll
        for (int ns = 0; ns < 4; ns++) {
          const int s_loc = ns * 16 + l16;
          const int sg = s0 + s_loc;
          const int sdoc = doc_s[s_loc];
#pragma unroll
          for (int r = 0; r < 4; r++) {
            const bool ok = (sg <= qg[qi][r]) && (sdoc == mydoc[qi][r]);
            const float p = ok ? __expf(S[ns][r] * scale) : 0.f;
            l_i[qi][r] += p;
            Pw[(quad * 4 + r) * PSTR + ns * 16 + l16] = f2bf(p);
          }
        }
      }

#pragma unroll
      for (int ks = 0; ks < 2; ks++) {
        short8 pf = *(const short8*)(Pw + l16 * PSTR + ks * 32 + quad * 8);
#pragma unroll
        for (int v8 = 0; v8 < 8; v8++) {
          short8 vf = *(const short8*)(Vt + (v8 * 16 + l16) * 64 + vcol[ks]);
          O[qi][v8] = __builtin_amdgcn_mfma_f32_16x16x32_bf16(pf, vf, O[qi][v8], 0, 0, 0);
        }
      }
    }  // qi
  }

#pragma unroll
  for (int qi = 0; qi < 2; qi++) {
#pragma unroll
    for (int off = 8; off >= 1; off >>= 1)
#pragma unroll
      for (int r = 0; r < 4; r++) l_i[qi][r] += __shfl_xor(l_i[qi][r], off);

#pragma unroll
    for (int r = 0; r < 4; r++) {
      const float inv = 1.f / l_i[qi][r];
      short* op = attn_out + (size_t)(b * TT + qg[qi][r]) * D_MODEL
                  + h * HEAD_DIM + l16;
#pragma unroll
      for (int v8 = 0; v8 < 8; v8++)
        op[v8 * 16] = f2bf(O[qi][v8][r] * inv);
    }
  }
}

// ---------------------------------------------------------------------------
extern "C" void kernel_launch(void* const* d_in, const int* in_sizes, int n_in,
                              void* d_out, int out_size, void* d_ws, size_t ws_size,
                              hipStream_t stream)
{
  const float* x     = (const float*)d_in[0];
  const float* sin_t = (const float*)d_in[1];
  const float* cos_t = (const float*)d_in[2];
  const int*   doc   = (const int*)  d_in[3];
  const float* W_qkv = (const float*)d_in[4];
  const float* W_out = (const float*)d_in[5];
  float* out = (float*)d_out;

  const int M = BB * TT;  // 4096

  char* p = (char*)d_ws;
  short* qkv_bf = (short*)p; p += (size_t)M * QKV_N * 2;
  short* xb     = (short*)p; p += (size_t)M * D_MODEL * 2;
  short* attn_bf = xb;  // alias: xb dead after GEMM1
  short* Vtb    = (short*)p; p += (size_t)BB * 128 * TT * 2;
  short* Wqkv_t = (short*)p; p += (size_t)QKV_N * D_MODEL * 2;
  short* Wout_t = (short*)p;

  // fused preps (BW-rebuilt round 10)
  prep_all<<<XC_BLOCKS + WQT_TILES + WOT_TILES, 256, 0, stream>>>(
      x, xb, W_qkv, Wqkv_t, W_out, Wout_t);

  // GEMM1 fused with RoPE + V-transpose epilogue (BK=64, 2-barrier)
  {
    dim3 grid(QKV_N / 128, M / 128);
    gemm_qkv_rope<<<grid, 256, 0, stream>>>(xb, Wqkv_t, qkv_bf, Vtb, sin_t, cos_t);
  }
  // flash attention (paired q-tiles, shared staging)
  {
    dim3 grid(TT / 128, NUM_HEADS, BB);   // 16 paired q-tile blocks
    attn_mfma<<<grid, 256, 0, stream>>>(qkv_bf, Vtb, doc, attn_bf);
  }
  // GEMM2 (BK=64, 2-barrier)
  {
    dim3 grid(D_MODEL / 128, M / 128);
    gemm_mfma_bt<<<grid, 256, 0, stream>>>(attn_bf, Wout_t, out, M, D_MODEL, D_MODEL);
  }
}